// Round 5
// baseline (449.473 us; speedup 1.0000x reference)
//
#include <hip/hip_runtime.h>
#include <cfloat>
#include <cmath>

#define B_ 64
#define N_ 8192
#define D_ 128
#define M_ 64
#define CROWS 64              // rows per chunk (LDS tile)
#define NCHUNK 4              // chunks per block
#define BROWS (CROWS*NCHUNK)  // 256 rows per block
#define NBLK (N_/BROWS)       // 32 blocks per batch
#define ALPHA_ 0.1f
#define EPS_ 1e-10f

typedef __attribute__((ext_vector_type(4))) float f32x4;
typedef __attribute__((ext_vector_type(8))) short bf16x8;
typedef __attribute__((ext_vector_type(4))) short s16x4;

static __device__ __forceinline__ short f2bf(float f) {
    unsigned u = __float_as_uint(f);
    u += 0x7fff + ((u >> 16) & 1);           // RNE to bf16
    return (short)(u >> 16);
}
static __device__ __forceinline__ float bf2f(short s) {
    return __uint_as_float(((unsigned)(unsigned short)s) << 16);
}

// Kernel 1: per (b, 256-row block): xp = x . pv^T via bf16x4-split MFMA,
// fused min over n of (x2[n] - 2*xp[n,m]).  p2[m] deferred to kernel 2.
__global__ __launch_bounds__(256, 2)
void protomin_mfma(const float* __restrict__ x, const float* __restrict__ pv,
                   float* __restrict__ wsv, int* __restrict__ wsa) {
    __shared__ short xhi[2][CROWS * D_];     // bf16 hi plane, swizzled
    __shared__ short xlo[2][CROWS * D_];     // bf16 lo plane, swizzled
    __shared__ float x2s[2][CROWS];
    __shared__ float redv[4][M_];
    __shared__ int   redp[4][M_];

    const int tid = threadIdx.x;
    const int w   = tid >> 6;                // wave 0..3
    const int l   = tid & 63;                // lane
    const int lm  = l & 15, lg = l >> 4;
    const int bid = blockIdx.x;
    const int b   = bid >> 5;                // NBLK = 32
    const int nbase = (bid & 31) * BROWS;

    const float* xblk = x + ((size_t)b * N_ + nbase) * D_;

    // ---- issue chunk-0 staging loads first (cover latency with B setup) ----
    f32x4 nv[8];
    {
        const f32x4* src = (const f32x4*)xblk;
#pragma unroll
        for (int i = 0; i < 8; ++i) nv[i] = src[(w * 8 + i) * 64 + l];
    }

    // ---- B fragments: pv split to bf16 hi/lo, kept in registers ----
    // B-frag layout (16x16x32): col m = lane&15, k = (lane>>4)*8 + j
    bf16x8 Bh[4][4], Bl[4][4];               // [mtile][ktile]
#pragma unroll
    for (int mt = 0; mt < 4; ++mt) {
#pragma unroll
        for (int kt = 0; kt < 4; ++kt) {
            const float* p = pv + (mt * 16 + lm) * D_ + kt * 32 + lg * 8;
            f32x4 p0 = *(const f32x4*)p;
            f32x4 p1 = *(const f32x4*)(p + 4);
#pragma unroll
            for (int j = 0; j < 4; ++j) {
                short h = f2bf(p0[j]);
                Bh[mt][kt][j] = h;
                Bl[mt][kt][j] = f2bf(p0[j] - bf2f(h));
            }
#pragma unroll
            for (int j = 0; j < 4; ++j) {
                short h = f2bf(p1[j]);
                Bh[mt][kt][4 + j] = h;
                Bl[mt][kt][4 + j] = f2bf(p1[j] - bf2f(h));
            }
        }
    }

    // stage: split nv -> bf16 hi/lo planes (swizzled) + fp32 x2 row sums
    auto stage = [&](int buf) {
#pragma unroll
        for (int i = 0; i < 8; ++i) {
            int seg = w * 8 + i;
            int row = seg * 2 + (l >> 5);    // chunk-local row
            int ks  = (l & 31) * 4;
            f32x4 v = nv[i];
            float s = v[0] * v[0];
            s = fmaf(v[1], v[1], s); s = fmaf(v[2], v[2], s); s = fmaf(v[3], v[3], s);
            s += __shfl_xor(s, 1);  s += __shfl_xor(s, 2);  s += __shfl_xor(s, 4);
            s += __shfl_xor(s, 8);  s += __shfl_xor(s, 16);
            if ((l & 31) == 0) x2s[buf][row] = s;
            s16x4 hv, lv;
#pragma unroll
            for (int j = 0; j < 4; ++j) {
                short h = f2bf(v[j]);
                hv[j] = h;
                lv[j] = f2bf(v[j] - bf2f(h));
            }
            int sidx = row * D_ + (ks ^ ((row & 7) << 3));   // XOR swizzle
            *(s16x4*)&xhi[buf][sidx] = hv;
            *(s16x4*)&xlo[buf][sidx] = lv;
        }
    };

    float bv[4]; int bp[4];
#pragma unroll
    for (int mt = 0; mt < 4; ++mt) { bv[mt] = FLT_MAX; bp[mt] = 0; }

    stage(0);
    __syncthreads();

    for (int c = 0; c < NCHUNK; ++c) {
        const int cur = c & 1;
        if (c + 1 < NCHUNK) {                // prefetch next chunk into regs
            const f32x4* src = (const f32x4*)(xblk + (size_t)(c + 1) * CROWS * D_);
#pragma unroll
            for (int i = 0; i < 8; ++i) nv[i] = src[(w * 8 + i) * 64 + l];
        }

        f32x4 acc[4] = {};                   // [mtile], C: col=lane&15, row=lg*4+reg
        const int arow  = w * 16 + lm;       // A-frag row (chunk-local)
        const int abase = arow * D_;
        const int aswz  = (arow & 7) << 3;
#pragma unroll
        for (int kt = 0; kt < 4; ++kt) {
            int koff = (kt * 32 + lg * 8) ^ aswz;
            bf16x8 ah = *(const bf16x8*)&xhi[cur][abase + koff];
            bf16x8 al = *(const bf16x8*)&xlo[cur][abase + koff];
#pragma unroll
            for (int mt = 0; mt < 4; ++mt) {
                acc[mt] = __builtin_amdgcn_mfma_f32_16x16x32_bf16(ah, Bh[mt][kt], acc[mt], 0, 0, 0);
                acc[mt] = __builtin_amdgcn_mfma_f32_16x16x32_bf16(al, Bh[mt][kt], acc[mt], 0, 0, 0);
                acc[mt] = __builtin_amdgcn_mfma_f32_16x16x32_bf16(ah, Bl[mt][kt], acc[mt], 0, 0, 0);
                acc[mt] = __builtin_amdgcn_mfma_f32_16x16x32_bf16(al, Bl[mt][kt], acc[mt], 0, 0, 0);
            }
        }

        // fold: cand = x2[n] - 2*xp ; rows = w*16 + lg*4 + r
        float x2v[4];
        const int rbase = w * 16 + lg * 4;
#pragma unroll
        for (int r = 0; r < 4; ++r) x2v[r] = x2s[cur][rbase + r];
        const int npos0 = nbase + c * CROWS + rbase;
#pragma unroll
        for (int mt = 0; mt < 4; ++mt) {
#pragma unroll
            for (int r = 0; r < 4; ++r) {
                float cand = fmaf(-2.f, acc[mt][r], x2v[r]);
                if (cand < bv[mt]) { bv[mt] = cand; bp[mt] = npos0 + r; }
            }
        }

        if (c + 1 < NCHUNK) stage(cur ^ 1);
        __syncthreads();
    }

    // cross-lane (row-group) reduce, tie -> smaller n
#pragma unroll
    for (int mt = 0; mt < 4; ++mt) {
        float v = bv[mt]; int p = bp[mt];
#pragma unroll
        for (int off = 16; off <= 32; off <<= 1) {
            float ov = __shfl_xor(v, off);
            int   op = __shfl_xor(p, off);
            if (ov < v || (ov == v && op < p)) { v = ov; p = op; }
        }
        if (l < 16) { redv[w][mt * 16 + l] = v; redp[w][mt * 16 + l] = p; }
    }
    __syncthreads();

    // cross-wave reduce; one entry per (b, block, m)
    if (tid < M_) {
        float v = redv[0][tid]; int p = redp[0][tid];
#pragma unroll
        for (int w2 = 1; w2 < 4; ++w2) {
            float ov = redv[w2][tid]; int op = redp[w2][tid];
            if (ov < v || (ov == v && op < p)) { v = ov; p = op; }
        }
        wsv[(size_t)bid * M_ + tid] = v;
        wsa[(size_t)bid * M_ + tid] = p;
    }
}

// Kernel 2: add p2[m], reduce blocks, sqrt/exp, per-batch argmin over m.
__global__ void finalize_kernel(const float* __restrict__ wsv,
                                const int* __restrict__ wsa,
                                const float* __restrict__ pv,
                                float* __restrict__ out) {
    const int b = blockIdx.x;
    const int m = threadIdx.x;

    float p2 = 0.f;
    const f32x4* pp = (const f32x4*)(pv + m * D_);
#pragma unroll 8
    for (int j = 0; j < 32; ++j) {
        f32x4 v = pp[j];
        p2 = fmaf(v[0], v[0], p2); p2 = fmaf(v[1], v[1], p2);
        p2 = fmaf(v[2], v[2], p2); p2 = fmaf(v[3], v[3], p2);
    }

    float v = FLT_MAX; int p = 0;
    for (int bc = 0; bc < NBLK; ++bc) {      // ascending n
        size_t idx = ((size_t)(b * NBLK + bc)) * M_ + m;
        float nv2 = wsv[idx]; int np = wsa[idx];
        if (nv2 < v || (nv2 == v && np < p)) { v = nv2; p = np; }
    }
    float dist = sqrtf(fmaxf(v + p2, 0.f));
    out[b * M_ + m] = expf(EPS_ - ALPHA_ * dist);

    __shared__ float sv[M_];
    __shared__ int   sa[M_];
    sv[m] = dist; sa[m] = p;
    __syncthreads();
    if (m == 0) {
        float best = FLT_MAX; int bpos = 0;
        for (int k = 0; k < M_; ++k)         // ascending m, strict < = first-min
            if (sv[k] < best) { best = sv[k]; bpos = sa[k]; }
        out[B_ * M_ + b] = (float)bpos;
    }
}

extern "C" void kernel_launch(void* const* d_in, const int* in_sizes, int n_in,
                              void* d_out, int out_size, void* d_ws, size_t ws_size,
                              hipStream_t stream) {
    const float* x  = (const float*)d_in[0];
    const float* pv = (const float*)d_in[1];
    float* out = (float*)d_out;

    float* wsv = (float*)d_ws;
    int*   wsa = (int*)((char*)d_ws + (size_t)B_ * NBLK * M_ * sizeof(float));

    hipLaunchKernelGGL(protomin_mfma, dim3(B_ * NBLK), dim3(256), 0, stream,
                       x, pv, wsv, wsa);
    hipLaunchKernelGGL(finalize_kernel, dim3(B_), dim3(M_), 0, stream,
                       wsv, wsa, pv, out);
}

// Round 9
// 377.265 us; speedup vs baseline: 1.1914x; 1.1914x over previous
//
#include <hip/hip_runtime.h>
#include <cfloat>
#include <cmath>

#define B_ 64
#define N_ 8192
#define D_ 128
#define M_ 64
#define CROWS 64              // rows per chunk (LDS tile)
#define NCHUNK 4              // chunks per block
#define BROWS (CROWS*NCHUNK)  // 256 rows per block
#define NBLK (N_/BROWS)       // 32 blocks per batch
#define ALPHA_ 0.1f
#define EPS_ 1e-10f

typedef __attribute__((ext_vector_type(4))) float f32x4;
typedef __attribute__((ext_vector_type(8))) short bf16x8;
typedef __attribute__((ext_vector_type(4))) short s16x4;

static __device__ __forceinline__ short f2bf(float f) {
    unsigned u = __float_as_uint(f);
    u += 0x7fff + ((u >> 16) & 1);           // RNE to bf16
    return (short)(u >> 16);
}
static __device__ __forceinline__ float bf2f(short s) {
    return __uint_as_float(((unsigned)(unsigned short)s) << 16);
}

// Kernel 1: per (b, 256-row block): xp = x . pv^T via bf16 hi/lo split MFMA,
// fused min over n of (x2[n] - 2*xp[n,m]).  p2[m] deferred to kernel 2.
// Wave tiling: wave w = (wr=w&1, wm=w>>1) owns rows [32wr,32wr+32) x cols
// [32wm,32wm+32) of each 64-row chunk -> B frags = 64 VGPR (was 128: spilled).
__global__ __launch_bounds__(256, 2)
void protomin_mfma(const float* __restrict__ x, const float* __restrict__ pv,
                   float* __restrict__ wsv, int* __restrict__ wsa) {
    __shared__ short xhi[2][CROWS * D_];     // bf16 hi plane, swizzled (32 KB)
    __shared__ short xlo[2][CROWS * D_];     // bf16 lo plane, swizzled (32 KB)
    __shared__ float x2s[2][CROWS];
    __shared__ float redv[2][M_];
    __shared__ int   redp[2][M_];

    const int tid = threadIdx.x;
    const int w   = tid >> 6;                // wave 0..3
    const int l   = tid & 63;                // lane
    const int lm  = l & 15, lg = l >> 4;
    const int wr  = w & 1;                   // row-half of chunk
    const int wm  = w >> 1;                  // col-half of protos
    const int bid = blockIdx.x;
    const int b   = bid >> 5;                // NBLK = 32
    const int nbase = (bid & 31) * BROWS;

    const float* xblk = x + ((size_t)b * N_ + nbase) * D_;

    // ---- issue chunk-0 staging loads first (cover latency with B setup) ----
    f32x4 nv[8];
    {
        const f32x4* src = (const f32x4*)xblk;
#pragma unroll
        for (int i = 0; i < 8; ++i) nv[i] = src[(w * 8 + i) * 64 + l];
    }

    // ---- B fragments: pv split to bf16 hi/lo, registers (2 mtiles/wave) ----
    // B-frag layout (16x16x32): col m = lane&15, k = (lane>>4)*8 + j
    bf16x8 Bh[2][4], Bl[2][4];               // [mtile][ktile] = 64 VGPR
#pragma unroll
    for (int mti = 0; mti < 2; ++mti) {
#pragma unroll
        for (int kt = 0; kt < 4; ++kt) {
            const float* p = pv + (wm * 32 + mti * 16 + lm) * D_ + kt * 32 + lg * 8;
            f32x4 p0 = *(const f32x4*)p;
            f32x4 p1 = *(const f32x4*)(p + 4);
#pragma unroll
            for (int j = 0; j < 4; ++j) {
                short h = f2bf(p0[j]);
                Bh[mti][kt][j] = h;
                Bl[mti][kt][j] = f2bf(p0[j] - bf2f(h));
            }
#pragma unroll
            for (int j = 0; j < 4; ++j) {
                short h = f2bf(p1[j]);
                Bh[mti][kt][4 + j] = h;
                Bl[mti][kt][4 + j] = f2bf(p1[j] - bf2f(h));
            }
        }
    }

    // stage: split nv -> bf16 hi/lo planes (swizzled) + fp32 x2 row sums
    auto stage = [&](int buf) {
#pragma unroll
        for (int i = 0; i < 8; ++i) {
            int seg = w * 8 + i;
            int row = seg * 2 + (l >> 5);    // chunk-local row
            int ks  = (l & 31) * 4;
            f32x4 v = nv[i];
            float s = v[0] * v[0];
            s = fmaf(v[1], v[1], s); s = fmaf(v[2], v[2], s); s = fmaf(v[3], v[3], s);
            s += __shfl_xor(s, 1);  s += __shfl_xor(s, 2);  s += __shfl_xor(s, 4);
            s += __shfl_xor(s, 8);  s += __shfl_xor(s, 16);
            if ((l & 31) == 0) x2s[buf][row] = s;
            s16x4 hv, lv;
#pragma unroll
            for (int j = 0; j < 4; ++j) {
                short h = f2bf(v[j]);
                hv[j] = h;
                lv[j] = f2bf(v[j] - bf2f(h));
            }
            int sidx = row * D_ + (ks ^ ((row & 7) << 3));   // XOR swizzle
            *(s16x4*)&xhi[buf][sidx] = hv;
            *(s16x4*)&xlo[buf][sidx] = lv;
        }
    };

    float bv[2]; int bp[2];
#pragma unroll
    for (int mti = 0; mti < 2; ++mti) { bv[mti] = FLT_MAX; bp[mti] = 0; }

    stage(0);
    __syncthreads();

    for (int c = 0; c < NCHUNK; ++c) {
        const int cur = c & 1;
        if (c + 1 < NCHUNK) {                // prefetch next chunk into regs
            const f32x4* src = (const f32x4*)(xblk + (size_t)(c + 1) * CROWS * D_);
#pragma unroll
            for (int i = 0; i < 8; ++i) nv[i] = src[(w * 8 + i) * 64 + l];
        }

        f32x4 acc[2][2] = {};                // [rt][mti]; C: col=lane&15, row=lg*4+reg
#pragma unroll
        for (int kt = 0; kt < 4; ++kt) {
            bf16x8 ah[2], al[2];
#pragma unroll
            for (int rt = 0; rt < 2; ++rt) {
                int arow = wr * 32 + rt * 16 + lm;           // chunk-local row
                int koff = (kt * 32 + lg * 8) ^ ((arow & 7) << 3);
                ah[rt] = *(const bf16x8*)&xhi[cur][arow * D_ + koff];
                al[rt] = *(const bf16x8*)&xlo[cur][arow * D_ + koff];
            }
#pragma unroll
            for (int rt = 0; rt < 2; ++rt) {
#pragma unroll
                for (int mti = 0; mti < 2; ++mti) {
                    acc[rt][mti] = __builtin_amdgcn_mfma_f32_16x16x32_bf16(ah[rt], Bh[mti][kt], acc[rt][mti], 0, 0, 0);
                    acc[rt][mti] = __builtin_amdgcn_mfma_f32_16x16x32_bf16(al[rt], Bh[mti][kt], acc[rt][mti], 0, 0, 0);
                    acc[rt][mti] = __builtin_amdgcn_mfma_f32_16x16x32_bf16(ah[rt], Bl[mti][kt], acc[rt][mti], 0, 0, 0);
                    acc[rt][mti] = __builtin_amdgcn_mfma_f32_16x16x32_bf16(al[rt], Bl[mti][kt], acc[rt][mti], 0, 0, 0);
                }
            }
        }

        // fold: cand = x2[n] - 2*xp ; rt ascending keeps n ascending for ties
#pragma unroll
        for (int rt = 0; rt < 2; ++rt) {
            const int rbase = wr * 32 + rt * 16 + lg * 4;
            float x2v[4];
#pragma unroll
            for (int r = 0; r < 4; ++r) x2v[r] = x2s[cur][rbase + r];
            const int npos0 = nbase + c * CROWS + rbase;
#pragma unroll
            for (int mti = 0; mti < 2; ++mti) {
#pragma unroll
                for (int r = 0; r < 4; ++r) {
                    float cand = fmaf(-2.f, acc[rt][mti][r], x2v[r]);
                    if (cand < bv[mti]) { bv[mti] = cand; bp[mti] = npos0 + r; }
                }
            }
        }

        if (c + 1 < NCHUNK) stage(cur ^ 1);
        __syncthreads();
    }

    // cross-lane reduce over lg (rows within 16-tile), tie -> smaller n
#pragma unroll
    for (int mti = 0; mti < 2; ++mti) {
        float v = bv[mti]; int p = bp[mti];
#pragma unroll
        for (int off = 16; off <= 32; off <<= 1) {
            float ov = __shfl_xor(v, off);
            int   op = __shfl_xor(p, off);
            if (ov < v || (ov == v && op < p)) { v = ov; p = op; }
        }
        if (l < 16) { redv[wr][wm * 32 + mti * 16 + l] = v;
                      redp[wr][wm * 32 + mti * 16 + l] = p; }
    }
    __syncthreads();

    // cross-wave (row-half) reduce; one entry per (b, block, m)
    if (tid < M_) {
        float v = redv[0][tid]; int p = redp[0][tid];
        float ov = redv[1][tid]; int op = redp[1][tid];
        if (ov < v || (ov == v && op < p)) { v = ov; p = op; }
        wsv[(size_t)bid * M_ + tid] = v;
        wsa[(size_t)bid * M_ + tid] = p;
    }
}

// Kernel 2: add p2[m], reduce blocks, sqrt/exp, per-batch argmin over m.
__global__ void finalize_kernel(const float* __restrict__ wsv,
                                const int* __restrict__ wsa,
                                const float* __restrict__ pv,
                                float* __restrict__ out) {
    const int b = blockIdx.x;
    const int m = threadIdx.x;

    float p2 = 0.f;
    const f32x4* pp = (const f32x4*)(pv + m * D_);
#pragma unroll 8
    for (int j = 0; j < 32; ++j) {
        f32x4 v = pp[j];
        p2 = fmaf(v[0], v[0], p2); p2 = fmaf(v[1], v[1], p2);
        p2 = fmaf(v[2], v[2], p2); p2 = fmaf(v[3], v[3], p2);
    }

    float v = FLT_MAX; int p = 0;
    for (int bc = 0; bc < NBLK; ++bc) {      // ascending n
        size_t idx = ((size_t)(b * NBLK + bc)) * M_ + m;
        float nv2 = wsv[idx]; int np = wsa[idx];
        if (nv2 < v || (nv2 == v && np < p)) { v = nv2; p = np; }
    }
    float dist = sqrtf(fmaxf(v + p2, 0.f));
    out[b * M_ + m] = expf(EPS_ - ALPHA_ * dist);

    __shared__ float sv[M_];
    __shared__ int   sa[M_];
    sv[m] = dist; sa[m] = p;
    __syncthreads();
    if (m == 0) {
        float best = FLT_MAX; int bpos = 0;
        for (int k = 0; k < M_; ++k)         // ascending m, strict < = first-min
            if (sv[k] < best) { best = sv[k]; bpos = sa[k]; }
        out[B_ * M_ + b] = (float)bpos;
    }
}

extern "C" void kernel_launch(void* const* d_in, const int* in_sizes, int n_in,
                              void* d_out, int out_size, void* d_ws, size_t ws_size,
                              hipStream_t stream) {
    const float* x  = (const float*)d_in[0];
    const float* pv = (const float*)d_in[1];
    float* out = (float*)d_out;

    float* wsv = (float*)d_ws;
    int*   wsa = (int*)((char*)d_ws + (size_t)B_ * NBLK * M_ * sizeof(float));

    hipLaunchKernelGGL(protomin_mfma, dim3(B_ * NBLK), dim3(256), 0, stream,
                       x, pv, wsv, wsa);
    hipLaunchKernelGGL(finalize_kernel, dim3(B_), dim3(M_), 0, stream,
                       wsv, wsa, pv, out);
}